// Round 1
// baseline (1146.001 us; speedup 1.0000x reference)
//
#include <hip/hip_runtime.h>
#include <stdint.h>

// Problem constants (N,C,H,W) = (32,256,56,56), 3x3 conv pad=1 stride=1
#define NB    32
#define C     256
#define HH    56
#define WW    56
#define HW    3136        // 56*56
#define P_TOT 100352      // NB*HW
#define CW    8           // 256 bits = 8 u32 words per pixel
#define EPSBN 1e-5f

// ---------------- pack activations: bit c = (x[n,c,h,w] >= 0) ----------------
__global__ __launch_bounds__(64) void pack_act(const float* __restrict__ x,
                                               uint32_t* __restrict__ px) {
    int p = blockIdx.x * 64 + threadIdx.x;          // pixel linear index (n*HW+rem)
    int n = p / HW, rem = p - n * HW;
    const float* xp = x + (size_t)n * C * HW + rem;
    uint32_t bits[CW];
#pragma unroll
    for (int wd = 0; wd < CW; ++wd) bits[wd] = 0u;
#pragma unroll 16
    for (int c = 0; c < C; ++c) {
        float v = xp[(size_t)c * HW];
        if (v >= 0.0f) bits[c >> 5] |= (1u << (c & 31));
    }
    uint4* dst = (uint4*)(px + (size_t)p * CW);
    dst[0] = make_uint4(bits[0], bits[1], bits[2], bits[3]);
    dst[1] = make_uint4(bits[4], bits[5], bits[6], bits[7]);
}

// ---------------- pack weights: pw[co][t][word], bit ci = (w[co,ci,t] >= 0) ---
__global__ __launch_bounds__(64) void pack_wgt(const float* __restrict__ w,
                                               uint32_t* __restrict__ pw) {
    int i = blockIdx.x * 64 + threadIdx.x;          // i = co*9 + t, 2304 total
    int co = i / 9, t = i - co * 9;
    const float* wp = w + (size_t)co * (C * 9) + t;
    uint32_t bits[CW];
#pragma unroll
    for (int wd = 0; wd < CW; ++wd) bits[wd] = 0u;
#pragma unroll 16
    for (int ci = 0; ci < C; ++ci) {
        float v = wp[(size_t)ci * 9];
        if (v >= 0.0f) bits[ci >> 5] |= (1u << (ci & 31));
    }
    uint4* dst = (uint4*)(pw + (size_t)i * CW);
    dst[0] = make_uint4(bits[0], bits[1], bits[2], bits[3]);
    dst[1] = make_uint4(bits[4], bits[5], bits[6], bits[7]);
}

// ---------------- binary conv via XNOR-popcount ------------------------------
// Each thread: one pixel, 64 output channels (co quarter from blockIdx.y).
// dot(n,co,h,w) = sum over valid taps of (256 - 2*popc(px_tap ^ pw[co][t]))
__global__ __launch_bounds__(64) void bconv(const uint32_t* __restrict__ px,
                                            const uint32_t* __restrict__ pw,
                                            short* __restrict__ sout) {
    int p = blockIdx.x * 64 + threadIdx.x;
    int n = p / HW, rem = p - n * HW;
    int h = rem / WW, w = rem - h * WW;

    uint64_t xt[9][4];
    int vmask[9];
#pragma unroll
    for (int t = 0; t < 9; ++t) {
        int dy = t / 3 - 1, dx = t % 3 - 1;
        int hh = h + dy, wx = w + dx;
        bool ok = (hh >= 0) && (hh < HH) && (wx >= 0) && (wx < WW);
        vmask[t] = ok ? ~0 : 0;
        if (ok) {
            const uint64_t* sp =
                (const uint64_t*)(px + (size_t)(n * HW + hh * WW + wx) * CW);
            xt[t][0] = sp[0]; xt[t][1] = sp[1]; xt[t][2] = sp[2]; xt[t][3] = sp[3];
        } else {
            xt[t][0] = 0; xt[t][1] = 0; xt[t][2] = 0; xt[t][3] = 0;
        }
    }

    int co0 = blockIdx.y * 64;
    short* op = sout + ((size_t)n * C + co0) * HW + rem;
#pragma unroll 2
    for (int c = 0; c < 64; ++c) {
        const uint64_t* wp = (const uint64_t*)(pw + (size_t)(co0 + c) * 9 * CW);
        int dot = 0;
#pragma unroll
        for (int t = 0; t < 9; ++t) {
            int pc = __popcll(xt[t][0] ^ wp[t * 4 + 0]) +
                     __popcll(xt[t][1] ^ wp[t * 4 + 1]) +
                     __popcll(xt[t][2] ^ wp[t * 4 + 2]) +
                     __popcll(xt[t][3] ^ wp[t * 4 + 3]);
            dot += (256 - 2 * pc) & vmask[t];
        }
        op[(size_t)c * HW] = (short)dot;
    }
}

// ---------------- per-channel BN stats from int16 conv output ----------------
// c = 0.5*s. mean m = 0.5*S/P ; var = 0.25*Q/P - m^2 (biased, as jnp.var)
// A = gamma*rsqrt(var+eps) ; B = beta - m*A  (so y = 0.5*s*A + B)
__global__ __launch_bounds__(256) void bnstats(const short* __restrict__ s,
                                               const float* __restrict__ g,
                                               const float* __restrict__ b,
                                               float* __restrict__ A,
                                               float* __restrict__ Bv) {
    int co = blockIdx.x;
    long long ssum = 0, ssq = 0;
    for (int n = 0; n < NB; ++n) {
        const short* base = s + ((size_t)n * C + co) * HW;
        for (int i = threadIdx.x; i < HW; i += 256) {
            int v = base[i];
            ssum += v;
            ssq += (long long)(v * v);
        }
    }
#pragma unroll
    for (int off = 32; off; off >>= 1) {
        ssum += __shfl_down(ssum, off, 64);
        ssq  += __shfl_down(ssq,  off, 64);
    }
    __shared__ long long red0[4];
    __shared__ long long red1[4];
    int lane = threadIdx.x & 63, wv = threadIdx.x >> 6;
    if (lane == 0) { red0[wv] = ssum; red1[wv] = ssq; }
    __syncthreads();
    if (threadIdx.x == 0) {
        long long S = red0[0] + red0[1] + red0[2] + red0[3];
        long long Q = red1[0] + red1[1] + red1[2] + red1[3];
        float m  = 0.5f  * (float)S / (float)P_TOT;
        float e2 = 0.25f * (float)Q / (float)P_TOT;
        float var = e2 - m * m;
        float inv = rsqrtf(var + EPSBN);
        float a = inv * g[co];
        A[co]  = a;
        Bv[co] = b[co] - m * a;
    }
}

// ---------------- bn1 + hardtanh + sign + repack ------------------------------
// sign(clip(y)) == sign(y); bit c = (0.5*s*A[c] + B[c] >= 0)
__global__ __launch_bounds__(64) void bnpack(const short* __restrict__ s,
                                             const float* __restrict__ A,
                                             const float* __restrict__ Bv,
                                             uint32_t* __restrict__ px) {
    int p = blockIdx.x * 64 + threadIdx.x;
    int n = p / HW, rem = p - n * HW;
    const short* sp = s + (size_t)n * C * HW + rem;
    uint32_t bits[CW];
#pragma unroll
    for (int wd = 0; wd < CW; ++wd) bits[wd] = 0u;
#pragma unroll 16
    for (int c = 0; c < C; ++c) {
        float y = 0.5f * (float)sp[(size_t)c * HW] * A[c] + Bv[c];
        if (y >= 0.0f) bits[c >> 5] |= (1u << (c & 31));
    }
    uint4* dst = (uint4*)(px + (size_t)p * CW);
    dst[0] = make_uint4(bits[0], bits[1], bits[2], bits[3]);
    dst[1] = make_uint4(bits[4], bits[5], bits[6], bits[7]);
}

// ---------------- bn2 + shortcut + hardtanh ----------------------------------
__global__ __launch_bounds__(256) void finalize(const short* __restrict__ s,
                                                const float* __restrict__ x,
                                                const float* __restrict__ A,
                                                const float* __restrict__ Bv,
                                                float* __restrict__ out) {
    int i = blockIdx.x * 256 + threadIdx.x;      // group of 4 elements
    int c = (i / 784) & 255;                     // 784 = 3136/4 groups per plane
    short4 sv = ((const short4*)s)[i];
    float4 xv = ((const float4*)x)[i];
    float a = A[c], bb = Bv[c];
    float4 o;
    o.x = fminf(1.0f, fmaxf(-1.0f, 0.5f * (float)sv.x * a + bb + xv.x));
    o.y = fminf(1.0f, fmaxf(-1.0f, 0.5f * (float)sv.y * a + bb + xv.y));
    o.z = fminf(1.0f, fmaxf(-1.0f, 0.5f * (float)sv.z * a + bb + xv.z));
    o.w = fminf(1.0f, fmaxf(-1.0f, 0.5f * (float)sv.w * a + bb + xv.w));
    ((float4*)out)[i] = o;
}

extern "C" void kernel_launch(void* const* d_in, const int* in_sizes, int n_in,
                              void* d_out, int out_size, void* d_ws, size_t ws_size,
                              hipStream_t stream) {
    const float* x  = (const float*)d_in[0];
    const float* w1 = (const float*)d_in[1];
    const float* g1 = (const float*)d_in[2];
    const float* b1 = (const float*)d_in[3];
    const float* w2 = (const float*)d_in[4];
    const float* g2 = (const float*)d_in[5];
    const float* b2 = (const float*)d_in[6];
    float* out = (float*)d_out;

    // workspace layout (all 256B-aligned-ish; total ~58 MB)
    char* ws = (char*)d_ws;
    uint32_t* pw1 = (uint32_t*)ws;  ws += 2304 * CW * 4;        // 73,728
    uint32_t* pw2 = (uint32_t*)ws;  ws += 2304 * CW * 4;        // 73,728
    float* A1 = (float*)ws;         ws += 1024;
    float* B1 = (float*)ws;         ws += 1024;
    float* A2 = (float*)ws;         ws += 1024;
    float* B2 = (float*)ws;         ws += 1024;
    uint32_t* px1 = (uint32_t*)ws;  ws += (size_t)P_TOT * CW * 4;   // 3,211,264
    uint32_t* px2 = (uint32_t*)ws;  ws += (size_t)P_TOT * CW * 4;   // 3,211,264
    short* s16 = (short*)ws;        // 51,380,224 (reused for conv1 and conv2)

    pack_act<<<P_TOT / 64, 64, 0, stream>>>(x, px1);
    pack_wgt<<<2304 / 64, 64, 0, stream>>>(w1, pw1);
    pack_wgt<<<2304 / 64, 64, 0, stream>>>(w2, pw2);

    bconv<<<dim3(P_TOT / 64, 4), 64, 0, stream>>>(px1, pw1, s16);
    bnstats<<<C, 256, 0, stream>>>(s16, g1, b1, A1, B1);
    bnpack<<<P_TOT / 64, 64, 0, stream>>>(s16, A1, B1, px2);

    bconv<<<dim3(P_TOT / 64, 4), 64, 0, stream>>>(px2, pw2, s16);
    bnstats<<<C, 256, 0, stream>>>(s16, g2, b2, A2, B2);

    finalize<<<(P_TOT * C / 4) / 256, 256, 0, stream>>>(s16, x, A2, B2, out);
}

// Round 2
// 958.924 us; speedup vs baseline: 1.1951x; 1.1951x over previous
//
#include <hip/hip_runtime.h>
#include <stdint.h>

// Problem constants (N,C,H,W) = (32,256,56,56), 3x3 conv pad=1 stride=1
#define NB    32
#define C     256
#define HH    56
#define WW    56
#define HW    3136        // 56*56
#define P_TOT 100352      // NB*HW
#define PH    58          // halo-padded height
#define PW    58          // halo-padded width
#define PHW   3364        // 58*58
#define CW    8           // 256 bits = 8 u32 words per pixel
#define EPSBN 1e-5f

// -------- pack activations into halo-padded bitplanes; halo cells = 0 --------
__global__ __launch_bounds__(64) void pack_act(const float* __restrict__ x,
                                               uint32_t* __restrict__ px) {
    int idx = blockIdx.x * 64 + threadIdx.x;        // 0 .. NB*PHW-1
    int n = idx / PHW, pp = idx - n * PHW;
    int ph = pp / PW, pw_ = pp - ph * PW;
    uint32_t bits[CW];
#pragma unroll
    for (int wd = 0; wd < CW; ++wd) bits[wd] = 0u;
    if (ph >= 1 && ph <= HH && pw_ >= 1 && pw_ <= WW) {
        const float* xp = x + (size_t)n * C * HW + (ph - 1) * WW + (pw_ - 1);
#pragma unroll 16
        for (int c = 0; c < C; ++c) {
            float v = xp[(size_t)c * HW];
            if (v >= 0.0f) bits[c >> 5] |= (1u << (c & 31));
        }
    }
    uint4* dst = (uint4*)(px + (size_t)idx * CW);
    dst[0] = make_uint4(bits[0], bits[1], bits[2], bits[3]);
    dst[1] = make_uint4(bits[4], bits[5], bits[6], bits[7]);
}

// ---------------- pack weights: pw[co][t][word], bit ci = (w[co,ci,t] >= 0) ---
__global__ __launch_bounds__(64) void pack_wgt(const float* __restrict__ w,
                                               uint32_t* __restrict__ pw) {
    int i = blockIdx.x * 64 + threadIdx.x;          // i = co*9 + t, 2304 total
    int co = i / 9, t = i - co * 9;
    const float* wp = w + (size_t)co * (C * 9) + t;
    uint32_t bits[CW];
#pragma unroll
    for (int wd = 0; wd < CW; ++wd) bits[wd] = 0u;
#pragma unroll 16
    for (int ci = 0; ci < C; ++ci) {
        float v = wp[(size_t)ci * 9];
        if (v >= 0.0f) bits[ci >> 5] |= (1u << (ci & 31));
    }
    uint4* dst = (uint4*)(pw + (size_t)i * CW);
    dst[0] = make_uint4(bits[0], bits[1], bits[2], bits[3]);
    dst[1] = make_uint4(bits[4], bits[5], bits[6], bits[7]);
}

// ------ border-correction table: K[pat][co] = 256*Tvalid + 2*sum_inv popc(w) --
// pat = pv*3+pq, pv: 0=top row,1=mid,2=bottom; pq: 0=left col,1=mid,2=right
__global__ __launch_bounds__(64) void build_K(const uint32_t* __restrict__ pw,
                                              unsigned short* __restrict__ Kt) {
    int i = blockIdx.x * 64 + threadIdx.x;          // 0..2303
    int pat = i >> 8, co = i & 255;
    int pv = pat / 3, pq = pat - pv * 3;
    int k = 0, corr = 0;
#pragma unroll
    for (int t = 0; t < 9; ++t) {
        int ty = t / 3, tx = t - ty * 3;
        bool inv = (pv == 0 && ty == 0) || (pv == 2 && ty == 2) ||
                   (pq == 0 && tx == 0) || (pq == 2 && tx == 2);
        if (inv) {
            ++k;
            const uint32_t* wp = pw + (size_t)(co * 9 + t) * CW;
#pragma unroll
            for (int wd = 0; wd < CW; ++wd) corr += __popc(wp[wd]);
        }
    }
    Kt[i] = (unsigned short)(256 * (9 - k) + 2 * corr);
}

// ---------------- binary conv via XNOR-popcount (halo padded input) ----------
// dot = K[pat][co] - 2 * sum_{t=0..8} popc(x_tap ^ w_t)
__global__ __launch_bounds__(256, 4) void bconv(const uint32_t* __restrict__ px,
                                                const uint32_t* __restrict__ pw,
                                                const unsigned short* __restrict__ Kt,
                                                short* __restrict__ sout) {
    int p = blockIdx.x * 256 + threadIdx.x;
    int n = p / HW, rem = p - n * HW;
    int h = rem / WW, w = rem - h * WW;

    const uint64_t* base =
        (const uint64_t*)(px + ((size_t)n * PHW + (size_t)(h + 1) * PW + (w + 1)) * CW);
    uint64_t xt[9][4];
#pragma unroll
    for (int t = 0; t < 9; ++t) {
        int dy = t / 3 - 1, dx = t - (t / 3) * 3 - 1;
        const uint64_t* sp = base + (ptrdiff_t)(dy * PW + dx) * 4;
        xt[t][0] = sp[0]; xt[t][1] = sp[1]; xt[t][2] = sp[2]; xt[t][3] = sp[3];
    }

    int pv = (h == 0) ? 0 : ((h == HH - 1) ? 2 : 1);
    int pq = (w == 0) ? 0 : ((w == WW - 1) ? 2 : 1);
    const unsigned short* Kp = Kt + (pv * 3 + pq) * 256;

    int co0 = blockIdx.y * 64;
    short* op = sout + ((size_t)n * C + co0) * HW + rem;
#pragma unroll 4
    for (int c = 0; c < 64; ++c) {
        const uint64_t* wq = (const uint64_t*)(pw + (size_t)(co0 + c) * 9 * CW);
        int r0 = 0, r1 = 0, r2 = 0, r3 = 0;
#pragma unroll
        for (int t = 0; t < 9; ++t) {
            r0 += __popcll(xt[t][0] ^ wq[t * 4 + 0]);
            r1 += __popcll(xt[t][1] ^ wq[t * 4 + 1]);
            r2 += __popcll(xt[t][2] ^ wq[t * 4 + 2]);
            r3 += __popcll(xt[t][3] ^ wq[t * 4 + 3]);
        }
        int dot = (int)Kp[co0 + c - co0 + c * 0 + (co0 + c) - (co0 + c) + (co0 + c)] ; // placeholder fixed below
        dot = (int)Kp[co0 + c] - 2 * (r0 + r1 + r2 + r3);
        op[(size_t)c * HW] = (short)dot;
    }
}

// ---------------- BN stats stage 1: per-(n,c) partial sums -------------------
__global__ __launch_bounds__(256) void stats1(const short* __restrict__ s,
                                              longlong2* __restrict__ part) {
    int bid = blockIdx.x;                           // bid = n*C + c
    const short* base = s + (size_t)bid * HW;
    int sum = 0;
    int sq = 0;
    for (int i = threadIdx.x; i < HW; i += 256) {
        int v = base[i];
        sum += v;
        sq += v * v;                                // <= 13*2304^2 = 6.9e7, fits
    }
    long long lsq = sq;
    long long lsum = sum;
#pragma unroll
    for (int off = 32; off; off >>= 1) {
        lsum += __shfl_down(lsum, off, 64);
        lsq  += __shfl_down(lsq,  off, 64);
    }
    __shared__ long long r0[4], r1[4];
    int lane = threadIdx.x & 63, wv = threadIdx.x >> 6;
    if (lane == 0) { r0[wv] = lsum; r1[wv] = lsq; }
    __syncthreads();
    if (threadIdx.x == 0) {
        longlong2 o;
        o.x = r0[0] + r0[1] + r0[2] + r0[3];
        o.y = r1[0] + r1[1] + r1[2] + r1[3];
        part[bid] = o;
    }
}

// ---------------- BN stats stage 2: finalize A (includes 0.5 factor), B ------
__global__ __launch_bounds__(256) void stats2(const longlong2* __restrict__ part,
                                              const float* __restrict__ g,
                                              const float* __restrict__ b,
                                              float* __restrict__ A,
                                              float* __restrict__ Bv) {
    int c = threadIdx.x;
    long long S = 0, Q = 0;
    for (int n = 0; n < NB; ++n) {
        longlong2 p = part[(size_t)n * C + c];
        S += p.x; Q += p.y;
    }
    float m  = 0.5f  * (float)S / (float)P_TOT;     // mean of 0.5*s
    float e2 = 0.25f * (float)Q / (float)P_TOT;     // E[(0.5 s)^2]
    float var = e2 - m * m;
    float a = g[c] * rsqrtf(var + EPSBN);
    A[c]  = 0.5f * a;                               // y = s*A + B
    Bv[c] = b[c] - m * a;
}

// -------- bn1 + hardtanh + sign + repack into halo-padded bitplanes ----------
__global__ __launch_bounds__(64) void bnpack(const short* __restrict__ s,
                                             const float* __restrict__ A,
                                             const float* __restrict__ Bv,
                                             uint32_t* __restrict__ px) {
    int idx = blockIdx.x * 64 + threadIdx.x;        // 0 .. NB*PHW-1
    int n = idx / PHW, pp = idx - n * PHW;
    int ph = pp / PW, pw_ = pp - ph * PW;
    uint32_t bits[CW];
#pragma unroll
    for (int wd = 0; wd < CW; ++wd) bits[wd] = 0u;
    if (ph >= 1 && ph <= HH && pw_ >= 1 && pw_ <= WW) {
        const short* sp = s + (size_t)n * C * HW + (ph - 1) * WW + (pw_ - 1);
#pragma unroll 16
        for (int c = 0; c < C; ++c) {
            float y = (float)sp[(size_t)c * HW] * A[c] + Bv[c];
            if (y >= 0.0f) bits[c >> 5] |= (1u << (c & 31));
        }
    }
    uint4* dst = (uint4*)(px + (size_t)idx * CW);
    dst[0] = make_uint4(bits[0], bits[1], bits[2], bits[3]);
    dst[1] = make_uint4(bits[4], bits[5], bits[6], bits[7]);
}

// ---------------- bn2 + shortcut + hardtanh ----------------------------------
__global__ __launch_bounds__(256) void finalize(const short* __restrict__ s,
                                                const float* __restrict__ x,
                                                const float* __restrict__ A,
                                                const float* __restrict__ Bv,
                                                float* __restrict__ out) {
    int i = blockIdx.x * 256 + threadIdx.x;      // group of 4 elements
    int c = (i / 784) & 255;                     // 784 = 3136/4 groups per plane
    short4 sv = ((const short4*)s)[i];
    float4 xv = ((const float4*)x)[i];
    float a = A[c], bb = Bv[c];
    float4 o;
    o.x = fminf(1.0f, fmaxf(-1.0f, (float)sv.x * a + bb + xv.x));
    o.y = fminf(1.0f, fmaxf(-1.0f, (float)sv.y * a + bb + xv.y));
    o.z = fminf(1.0f, fmaxf(-1.0f, (float)sv.z * a + bb + xv.z));
    o.w = fminf(1.0f, fmaxf(-1.0f, (float)sv.w * a + bb + xv.w));
    ((float4*)out)[i] = o;
}

extern "C" void kernel_launch(void* const* d_in, const int* in_sizes, int n_in,
                              void* d_out, int out_size, void* d_ws, size_t ws_size,
                              hipStream_t stream) {
    const float* x  = (const float*)d_in[0];
    const float* w1 = (const float*)d_in[1];
    const float* g1 = (const float*)d_in[2];
    const float* b1 = (const float*)d_in[3];
    const float* w2 = (const float*)d_in[4];
    const float* g2 = (const float*)d_in[5];
    const float* b2 = (const float*)d_in[6];
    float* out = (float*)d_out;

    // workspace layout (~58.6 MB total)
    char* ws = (char*)d_ws;
    uint32_t* pw1 = (uint32_t*)ws;        ws += 2304 * CW * 4;            // 73,728
    uint32_t* pw2 = (uint32_t*)ws;        ws += 2304 * CW * 4;            // 73,728
    unsigned short* Kt1 = (unsigned short*)ws; ws += 8192;                // 9*256*2 used
    unsigned short* Kt2 = (unsigned short*)ws; ws += 8192;
    float* A1 = (float*)ws;               ws += 1024;
    float* B1 = (float*)ws;               ws += 1024;
    float* A2 = (float*)ws;               ws += 1024;
    float* B2 = (float*)ws;               ws += 1024;
    longlong2* part = (longlong2*)ws;     ws += (size_t)NB * C * 16;      // 131,072
    uint32_t* px1 = (uint32_t*)ws;        ws += (size_t)NB * PHW * CW * 4; // 3,444,736
    uint32_t* px2 = (uint32_t*)ws;        ws += (size_t)NB * PHW * CW * 4; // 3,444,736
    short* s16 = (short*)ws;              // 51,380,224 (reused conv1/conv2)

    pack_act<<<(NB * PHW) / 64, 64, 0, stream>>>(x, px1);
    pack_wgt<<<2304 / 64, 64, 0, stream>>>(w1, pw1);
    pack_wgt<<<2304 / 64, 64, 0, stream>>>(w2, pw2);
    build_K<<<2304 / 64, 64, 0, stream>>>(pw1, Kt1);
    build_K<<<2304 / 64, 64, 0, stream>>>(pw2, Kt2);

    bconv<<<dim3(P_TOT / 256, 4), 256, 0, stream>>>(px1, pw1, Kt1, s16);
    stats1<<<NB * C, 256, 0, stream>>>(s16, part);
    stats2<<<1, 256, 0, stream>>>(part, g1, b1, A1, B1);
    bnpack<<<(NB * PHW) / 64, 64, 0, stream>>>(s16, A1, B1, px2);

    bconv<<<dim3(P_TOT / 256, 4), 256, 0, stream>>>(px2, pw2, Kt2, s16);
    stats1<<<NB * C, 256, 0, stream>>>(s16, part);
    stats2<<<1, 256, 0, stream>>>(part, g2, b2, A2, B2);

    finalize<<<(P_TOT * C / 4) / 256, 256, 0, stream>>>(s16, x, A2, B2, out);
}

// Round 3
// 715.814 us; speedup vs baseline: 1.6010x; 1.3396x over previous
//
#include <hip/hip_runtime.h>
#include <stdint.h>

// Problem constants (N,C,H,W) = (32,256,56,56), 3x3 conv pad=1 stride=1
#define NB    32
#define C     256
#define HH    56
#define WW    56
#define HW    3136        // 56*56
#define P_TOT 100352      // NB*HW
#define PW    58          // halo-padded width
#define PHW   3364        // 58*58
#define NPAD  107648      // NB*PHW
#define EPSBN 1e-5f

// ============ pack weights (both sets) via ballot: 1 wave per (set,co,t,wd) ==
// pw layout: [wd][co][10] u64 (pad 9->10 for 80B stride). popc: [co*9+t]*4+wd
__global__ __launch_bounds__(256) void pack_wgt(const float* __restrict__ w1,
                                                const float* __restrict__ w2,
                                                uint64_t* __restrict__ pw1,
                                                uint64_t* __restrict__ pw2,
                                                int* __restrict__ pc1,
                                                int* __restrict__ pc2) {
    int gw = blockIdx.x * 4 + (threadIdx.x >> 6);   // global wave 0..18431
    int lane = threadIdx.x & 63;
    int set = gw / 9216;
    int r = gw - set * 9216;
    int wd = r & 3, q = r >> 2;
    int t = q % 9, co = q / 9;
    const float* w = set ? w2 : w1;
    float v = w[(size_t)co * 2304 + (size_t)(wd * 64 + lane) * 9 + t];
    unsigned long long m = __ballot(v >= 0.0f);
    if (lane == 0) {
        uint64_t* pw = set ? pw2 : pw1;
        int* pc = set ? pc2 : pc1;
        pw[(size_t)(wd * 256 + co) * 10 + t] = m;
        pc[(co * 9 + t) * 4 + wd] = (int)__popcll(m);
    }
}

// ====== border-correction: K[pat][co] = 256*Tvalid + 2*sum_{t inv} popc(w_t) =
__global__ __launch_bounds__(256) void build_K(const int* __restrict__ pc1,
                                               const int* __restrict__ pc2,
                                               unsigned short* __restrict__ K1,
                                               unsigned short* __restrict__ K2) {
    int tid = blockIdx.x * 256 + threadIdx.x;       // 0..4607
    int set = tid / 2304;
    int r = tid - set * 2304;
    int pat = r >> 8, co = r & 255;
    int pv = pat / 3, pq = pat - pv * 3;
    const int* pc = set ? pc2 : pc1;
    int k = 0, corr = 0;
#pragma unroll
    for (int t = 0; t < 9; ++t) {
        int ty = t / 3, tx = t - ty * 3;
        bool inv = (pv == 0 && ty == 0) || (pv == 2 && ty == 2) ||
                   (pq == 0 && tx == 0) || (pq == 2 && tx == 2);
        if (inv) {
            ++k;
            const int* p = pc + (co * 9 + t) * 4;
            corr += p[0] + p[1] + p[2] + p[3];
        }
    }
    unsigned short* K = set ? K2 : K1;
    K[pat * 256 + co] = (unsigned short)(256 * (9 - k) + 2 * corr);
}

// ========== pack activations into 4 halo-padded u64 planes: px[wd][idx] ======
__global__ __launch_bounds__(256) void pack_act(const float* __restrict__ x,
                                                uint64_t* __restrict__ px) {
    int idx = blockIdx.x * 256 + threadIdx.x;       // padded pixel 0..NPAD-1
    if (idx >= NPAD) return;
    int n = idx / PHW, pp = idx - n * PHW;
    int ph = pp / PW, pw_ = pp - ph * PW;
    uint32_t bits[8];
#pragma unroll
    for (int wd = 0; wd < 8; ++wd) bits[wd] = 0u;
    if (ph >= 1 && ph <= HH && pw_ >= 1 && pw_ <= WW) {
        const float* xp = x + (size_t)n * C * HW + (ph - 1) * WW + (pw_ - 1);
#pragma unroll 16
        for (int c = 0; c < C; ++c) {
            float v = xp[(size_t)c * HW];
            if (v >= 0.0f) bits[c >> 5] |= (1u << (c & 31));
        }
    }
#pragma unroll
    for (int wd = 0; wd < 4; ++wd)
        px[(size_t)wd * NPAD + idx] =
            ((uint64_t)bits[2 * wd + 1] << 32) | bits[2 * wd];
}

// ================= binary conv via XNOR-popcount, word-split =================
// Thread: 1 pixel x 32 output channels (blockIdx.y octant).
// Outer loop wd (4 u64 planes): 9 taps resident (18 VGPR), acc[32] static.
__global__ __launch_bounds__(256, 4) void bconv(const uint64_t* __restrict__ px,
                                                const uint64_t* __restrict__ pw,
                                                const unsigned short* __restrict__ Kt,
                                                short* __restrict__ sout) {
    int p = blockIdx.x * 256 + threadIdx.x;
    int n = p / HW, rem = p - n * HW;
    int h = rem / WW, w = rem - h * WW;
    size_t pp = (size_t)n * PHW + (size_t)(h + 1) * PW + (w + 1);
    int co0 = blockIdx.y * 32;

    int acc[32];
#pragma unroll
    for (int c = 0; c < 32; ++c) acc[c] = 0;

#pragma unroll 1
    for (int wd = 0; wd < 4; ++wd) {
        const uint64_t* xb = px + (size_t)wd * NPAD + pp;
        uint64_t x0 = xb[-PW - 1], x1 = xb[-PW], x2 = xb[-PW + 1];
        uint64_t x3 = xb[-1],      x4 = xb[0],   x5 = xb[1];
        uint64_t x6 = xb[PW - 1],  x7 = xb[PW],  x8 = xb[PW + 1];
        const uint64_t* wb = pw + (size_t)(wd * 256 + co0) * 10;
#pragma unroll
        for (int c = 0; c < 32; ++c) {
            const uint64_t* wq = wb + (size_t)c * 10;
            int r = acc[c];
            r += __popcll(x0 ^ wq[0]);
            r += __popcll(x1 ^ wq[1]);
            r += __popcll(x2 ^ wq[2]);
            r += __popcll(x3 ^ wq[3]);
            r += __popcll(x4 ^ wq[4]);
            r += __popcll(x5 ^ wq[5]);
            r += __popcll(x6 ^ wq[6]);
            r += __popcll(x7 ^ wq[7]);
            r += __popcll(x8 ^ wq[8]);
            acc[c] = r;
        }
    }

    int pv = (h == 0) ? 0 : ((h == HH - 1) ? 2 : 1);
    int pq = (w == 0) ? 0 : ((w == WW - 1) ? 2 : 1);
    const unsigned short* Kp = Kt + (pv * 3 + pq) * 256 + co0;
    short* op = sout + ((size_t)n * C + co0) * HW + rem;
#pragma unroll
    for (int c = 0; c < 32; ++c)
        op[(size_t)c * HW] = (short)((int)Kp[c] - 2 * acc[c]);
}

// ===== BN stats, one block per channel, int4 loads, fused A/B finalize =======
// y = s*A[c] + B[c]  with  A = 0.5*gamma*rsqrt(var+eps), B = beta - m*(2A)
__global__ __launch_bounds__(256) void stats(const short* __restrict__ s,
                                             const float* __restrict__ g,
                                             const float* __restrict__ b,
                                             float* __restrict__ A,
                                             float* __restrict__ Bv) {
    int c = blockIdx.x;
    int sum = 0;
    long long sq = 0;
    for (int k = threadIdx.x; k < 12544; k += 256) {      // 12544 = P_TOT/8
        int n = k / 392, rr = k - n * 392;                // 392 = HW/8
        const int4* p =
            (const int4*)(s + ((size_t)n * C + c) * HW + rr * 8);
        int4 v = *p;
#pragma unroll
        for (int j = 0; j < 4; ++j) {
            int u = (&v.x)[j];
            int s0 = (int)(short)(u & 0xFFFF);
            int s1 = u >> 16;
            sum += s0 + s1;
            sq += (long long)(s0 * s0 + s1 * s1);
        }
    }
    long long lsum = sum;
#pragma unroll
    for (int off = 32; off; off >>= 1) {
        lsum += __shfl_down(lsum, off, 64);
        sq   += __shfl_down(sq,   off, 64);
    }
    __shared__ long long r0[4], r1[4];
    int lane = threadIdx.x & 63, wv = threadIdx.x >> 6;
    if (lane == 0) { r0[wv] = lsum; r1[wv] = sq; }
    __syncthreads();
    if (threadIdx.x == 0) {
        long long S = r0[0] + r0[1] + r0[2] + r0[3];
        long long Q = r1[0] + r1[1] + r1[2] + r1[3];
        float m  = 0.5f  * (float)S / (float)P_TOT;
        float e2 = 0.25f * (float)Q / (float)P_TOT;
        float var = e2 - m * m;
        float a = g[c] * rsqrtf(var + EPSBN);
        A[c]  = 0.5f * a;
        Bv[c] = b[c] - m * a;
    }
}

// ====== bn1 + hardtanh + sign + repack into halo-padded u64 planes ===========
__global__ __launch_bounds__(256) void bnpack(const short* __restrict__ s,
                                              const float* __restrict__ A,
                                              const float* __restrict__ Bv,
                                              uint64_t* __restrict__ px) {
    int idx = blockIdx.x * 256 + threadIdx.x;
    if (idx >= NPAD) return;
    int n = idx / PHW, pp = idx - n * PHW;
    int ph = pp / PW, pw_ = pp - ph * PW;
    uint32_t bits[8];
#pragma unroll
    for (int wd = 0; wd < 8; ++wd) bits[wd] = 0u;
    if (ph >= 1 && ph <= HH && pw_ >= 1 && pw_ <= WW) {
        const short* sp = s + (size_t)n * C * HW + (ph - 1) * WW + (pw_ - 1);
#pragma unroll 16
        for (int c = 0; c < C; ++c) {
            float y = (float)sp[(size_t)c * HW] * A[c] + Bv[c];
            if (y >= 0.0f) bits[c >> 5] |= (1u << (c & 31));
        }
    }
#pragma unroll
    for (int wd = 0; wd < 4; ++wd)
        px[(size_t)wd * NPAD + idx] =
            ((uint64_t)bits[2 * wd + 1] << 32) | bits[2 * wd];
}

// ---------------- bn2 + shortcut + hardtanh ----------------------------------
__global__ __launch_bounds__(256) void finalize(const short* __restrict__ s,
                                                const float* __restrict__ x,
                                                const float* __restrict__ A,
                                                const float* __restrict__ Bv,
                                                float* __restrict__ out) {
    int i = blockIdx.x * 256 + threadIdx.x;      // group of 4 elements
    int c = (i / 784) & 255;                     // 784 = 3136/4 groups per plane
    short4 sv = ((const short4*)s)[i];
    float4 xv = ((const float4*)x)[i];
    float a = A[c], bb = Bv[c];
    float4 o;
    o.x = fminf(1.0f, fmaxf(-1.0f, (float)sv.x * a + bb + xv.x));
    o.y = fminf(1.0f, fmaxf(-1.0f, (float)sv.y * a + bb + xv.y));
    o.z = fminf(1.0f, fmaxf(-1.0f, (float)sv.z * a + bb + xv.z));
    o.w = fminf(1.0f, fmaxf(-1.0f, (float)sv.w * a + bb + xv.w));
    ((float4*)out)[i] = o;
}

extern "C" void kernel_launch(void* const* d_in, const int* in_sizes, int n_in,
                              void* d_out, int out_size, void* d_ws, size_t ws_size,
                              hipStream_t stream) {
    const float* x  = (const float*)d_in[0];
    const float* w1 = (const float*)d_in[1];
    const float* g1 = (const float*)d_in[2];
    const float* b1 = (const float*)d_in[3];
    const float* w2 = (const float*)d_in[4];
    const float* g2 = (const float*)d_in[5];
    const float* b2 = (const float*)d_in[6];
    float* out = (float*)d_out;

    // workspace layout (~58.5 MB)
    char* ws = (char*)d_ws;
    uint64_t* pw1 = (uint64_t*)ws;          ws += 4 * 256 * 10 * 8;   // 81,920
    uint64_t* pw2 = (uint64_t*)ws;          ws += 4 * 256 * 10 * 8;
    int* pc1 = (int*)ws;                    ws += 9216 * 4;           // 36,864
    int* pc2 = (int*)ws;                    ws += 9216 * 4;
    unsigned short* K1 = (unsigned short*)ws; ws += 8192;
    unsigned short* K2 = (unsigned short*)ws; ws += 8192;
    float* A1 = (float*)ws;                 ws += 1024;
    float* B1 = (float*)ws;                 ws += 1024;
    float* A2 = (float*)ws;                 ws += 1024;
    float* B2 = (float*)ws;                 ws += 1024;
    uint64_t* px1 = (uint64_t*)ws;          ws += (size_t)4 * NPAD * 8; // 3,444,736
    uint64_t* px2 = (uint64_t*)ws;          ws += (size_t)4 * NPAD * 8;
    short* s16 = (short*)ws;                // 51,380,224

    pack_wgt<<<4608, 256, 0, stream>>>(w1, w2, pw1, pw2, pc1, pc2);
    build_K<<<18, 256, 0, stream>>>(pc1, pc2, K1, K2);
    pack_act<<<(NPAD + 255) / 256, 256, 0, stream>>>(x, px1);

    bconv<<<dim3(P_TOT / 256, 8), 256, 0, stream>>>(px1, pw1, K1, s16);
    stats<<<C, 256, 0, stream>>>(s16, g1, b1, A1, B1);
    bnpack<<<(NPAD + 255) / 256, 256, 0, stream>>>(s16, A1, B1, px2);

    bconv<<<dim3(P_TOT / 256, 8), 256, 0, stream>>>(px2, pw2, K2, s16);
    stats<<<C, 256, 0, stream>>>(s16, g2, b2, A2, B2);

    finalize<<<(P_TOT * C / 4) / 256, 256, 0, stream>>>(s16, x, A2, B2, out);
}

// Round 5
// 566.382 us; speedup vs baseline: 2.0234x; 1.2638x over previous
//
#include <hip/hip_runtime.h>
#include <stdint.h>

// Problem constants (N,C,H,W) = (32,256,56,56), 3x3 conv pad=1 stride=1
#define NB    32
#define C     256
#define HH    56
#define WW    56
#define HW    3136        // 56*56
#define P_TOT 100352      // NB*HW
#define PW    58          // halo-padded width
#define PHW   3364        // 58*58
#define NPAD  107648      // NB*PHW
#define EPSBN 1e-5f

// ---------------- 64-lane u64 shuffle + 64x64 bit-matrix transpose -----------
__device__ __forceinline__ uint64_t shflx64(uint64_t v, int m) {
    int lo = __shfl_xor((int)(uint32_t)v, m, 64);
    int hi = __shfl_xor((int)(uint32_t)(v >> 32), m, 64);
    return ((uint64_t)(uint32_t)hi << 32) | (uint32_t)lo;
}
// Input: lane i holds bits j. Output: lane j holds bits i.
__device__ __forceinline__ uint64_t bt64(uint64_t M, int lane) {
    const uint64_t mk[6] = {0x5555555555555555ULL, 0x3333333333333333ULL,
                            0x0F0F0F0F0F0F0F0FULL, 0x00FF00FF00FF00FFULL,
                            0x0000FFFF0000FFFFULL, 0x00000000FFFFFFFFULL};
#pragma unroll
    for (int k = 0; k < 6; ++k) {
        int s = 1 << k;
        uint64_t mA = mk[k];
        uint64_t v = shflx64(M, s);
        M = (lane & s) ? ((M & ~mA) | ((v & ~mA) >> s))
                       : ((M &  mA) | ((v &  mA) << s));
    }
    return M;
}

// ============ pack weights (both sets) via ballot: 1 wave per (set,co,t,wd) ==
// pw layout: [wd][co][10] u64 (pad 9->10). popcount table pc: [co*9+t]*4+wd
__global__ __launch_bounds__(256) void pack_wgt(const float* __restrict__ w1,
                                                const float* __restrict__ w2,
                                                uint64_t* __restrict__ pw1,
                                                uint64_t* __restrict__ pw2,
                                                int* __restrict__ pc1,
                                                int* __restrict__ pc2) {
    int gw = blockIdx.x * 4 + (threadIdx.x >> 6);   // global wave 0..18431
    int lane = threadIdx.x & 63;
    int set = gw / 9216;
    int r = gw - set * 9216;
    int wd = r & 3, q = r >> 2;
    int t = q % 9, co = q / 9;
    const float* w = set ? w2 : w1;
    float v = w[(size_t)co * 2304 + (size_t)(wd * 64 + lane) * 9 + t];
    unsigned long long m = __ballot(v >= 0.0f);
    if (lane == 0) {
        uint64_t* pw = set ? pw2 : pw1;
        int* pc = set ? pc2 : pc1;
        pw[(size_t)(wd * 256 + co) * 10 + t] = m;
        pc[(co * 9 + t) * 4 + wd] = (int)__popcll(m);
    }
}

// ====== border-correction: K[pat][co] = 256*Tvalid + 2*sum_{t inv} popc(w_t) =
__global__ __launch_bounds__(256) void build_K(const int* __restrict__ pc1,
                                               const int* __restrict__ pc2,
                                               unsigned short* __restrict__ K1,
                                               unsigned short* __restrict__ K2) {
    int tid = blockIdx.x * 256 + threadIdx.x;       // 0..4607
    int set = tid / 2304;
    int r = tid - set * 2304;
    int pat = r >> 8, co = r & 255;
    int pv = pat / 3, pq = pat - pv * 3;
    const int* pc = set ? pc2 : pc1;
    int k = 0, corr = 0;
#pragma unroll
    for (int t = 0; t < 9; ++t) {
        int ty = t / 3, tx = t - ty * 3;
        bool inv = (pv == 0 && ty == 0) || (pv == 2 && ty == 2) ||
                   (pq == 0 && tx == 0) || (pq == 2 && tx == 2);
        if (inv) {
            ++k;
            const int* p = pc + (co * 9 + t) * 4;
            corr += p[0] + p[1] + p[2] + p[3];
        }
    }
    unsigned short* K = set ? K2 : K1;
    K[pat * 256 + co] = (unsigned short)(256 * (9 - k) + 2 * corr);
}

// =========== zero the halo cells of both packed-activation buffers ===========
__global__ __launch_bounds__(256) void zero_halo(uint64_t* __restrict__ px1,
                                                 uint64_t* __restrict__ px2) {
    int idx = blockIdx.x * 256 + threadIdx.x;       // 0..NPAD-1
    if (idx >= NPAD) return;
    int pp = idx % PHW;
    int ph = pp / PW, pw_ = pp - ph * PW;
    if (ph == 0 || ph == PW - 1 || pw_ == 0 || pw_ == PW - 1) {
#pragma unroll
        for (int wd = 0; wd < 4; ++wd) {
            px1[(size_t)wd * NPAD + idx] = 0ull;
            px2[(size_t)wd * NPAD + idx] = 0ull;
        }
    }
}

// ==== pack activations: ballot over coalesced pixel-loads + bit transpose ====
// wave -> (pixel group g of 64, channel chunk wd). lane = pixel.
__global__ __launch_bounds__(256) void pack_act(const float* __restrict__ x,
                                                uint64_t* __restrict__ px) {
    int wid = blockIdx.x * 4 + (threadIdx.x >> 6);  // 0..6271
    int lane = threadIdx.x & 63;
    int wd = wid & 3;
    int g = wid >> 2;                               // 0..1567
    int n = g / 49, gi = g - n * 49;
    const float* xp = x + ((size_t)n * C + wd * 64) * HW + gi * 64 + lane;
    uint64_t M = 0;
#pragma unroll
    for (int c = 0; c < 64; ++c) {
        float v = xp[(size_t)c * HW];
        unsigned long long m = __ballot(v >= 0.0f);
        if (lane == c) M = m;                       // cndmask select
    }
    M = bt64(M, lane);                              // lane p: bit c = sign
    int p = gi * 64 + lane;
    int h = p / WW, w = p - h * WW;
    px[(size_t)wd * NPAD + (size_t)n * PHW + (size_t)(h + 1) * PW + (w + 1)] = M;
}

// ================= binary conv via XNOR-popcount, word-split =================
// Thread: 1 pixel x 64 output channels (blockIdx.y quadrant).
// Weights for the whole co-block staged in LDS (uniform-address broadcast).
__global__ __launch_bounds__(256, 3) void bconv(const uint64_t* __restrict__ px,
                                                const uint64_t* __restrict__ pw,
                                                const unsigned short* __restrict__ Kt,
                                                short* __restrict__ sout) {
    __shared__ uint64_t lw[2560];                   // [wd][64 co][10]
    int co0 = blockIdx.y * 64;
#pragma unroll 1
    for (int i = threadIdx.x; i < 2560; i += 256) {
        int wd = i / 640, j = i - wd * 640;
        lw[i] = pw[(size_t)(wd * 256 + co0) * 10 + j];
    }
    __syncthreads();

    int p = blockIdx.x * 256 + threadIdx.x;
    int n = p / HW, rem = p - n * HW;
    int h = rem / WW, w = rem - h * WW;
    size_t pp = (size_t)n * PHW + (size_t)(h + 1) * PW + (w + 1);

    int acc[64];
#pragma unroll
    for (int c = 0; c < 64; ++c) acc[c] = 0;

#pragma unroll 1
    for (int wd = 0; wd < 4; ++wd) {
        const uint64_t* xb = px + (size_t)wd * NPAD + pp;
        uint64_t x0 = xb[-PW - 1], x1 = xb[-PW], x2 = xb[-PW + 1];
        uint64_t x3 = xb[-1],      x4 = xb[0],   x5 = xb[1];
        uint64_t x6 = xb[PW - 1],  x7 = xb[PW],  x8 = xb[PW + 1];
        const uint64_t* wb = lw + wd * 640;
#pragma unroll
        for (int c = 0; c < 64; ++c) {
            const uint64_t* wq = wb + c * 10;
            int r = acc[c];
            r += __popcll(x0 ^ wq[0]);
            r += __popcll(x1 ^ wq[1]);
            r += __popcll(x2 ^ wq[2]);
            r += __popcll(x3 ^ wq[3]);
            r += __popcll(x4 ^ wq[4]);
            r += __popcll(x5 ^ wq[5]);
            r += __popcll(x6 ^ wq[6]);
            r += __popcll(x7 ^ wq[7]);
            r += __popcll(x8 ^ wq[8]);
            acc[c] = r;
        }
    }

    int pv = (h == 0) ? 0 : ((h == HH - 1) ? 2 : 1);
    int pq = (w == 0) ? 0 : ((w == WW - 1) ? 2 : 1);
    const unsigned short* Kp = Kt + (pv * 3 + pq) * 256 + co0;
    short* op = sout + ((size_t)n * C + co0) * HW + rem;
#pragma unroll
    for (int c = 0; c < 64; ++c)
        op[(size_t)c * HW] = (short)((int)Kp[c] - 2 * acc[c]);
}

// ===== BN stats, one block per channel, int4 loads, fused A/B finalize =======
__global__ __launch_bounds__(256) void stats(const short* __restrict__ s,
                                             const float* __restrict__ g,
                                             const float* __restrict__ b,
                                             float* __restrict__ A,
                                             float* __restrict__ Bv) {
    int c = blockIdx.x;
    int sum = 0;
    long long sq = 0;
#pragma unroll 4
    for (int k = threadIdx.x; k < 12544; k += 256) {      // 12544 = P_TOT/8
        int n = k / 392, rr = k - n * 392;                // 392 = HW/8
        const int4* p = (const int4*)(s + ((size_t)n * C + c) * HW + rr * 8);
        int4 v = *p;
#pragma unroll
        for (int j = 0; j < 4; ++j) {
            int u = (&v.x)[j];
            int s0 = (int)(short)(u & 0xFFFF);
            int s1 = u >> 16;
            sum += s0 + s1;
            sq += (long long)(s0 * s0 + s1 * s1);
        }
    }
    long long lsum = sum;
#pragma unroll
    for (int off = 32; off; off >>= 1) {
        lsum += __shfl_down(lsum, off, 64);
        sq   += __shfl_down(sq,   off, 64);
    }
    __shared__ long long r0[4], r1[4];
    int lane = threadIdx.x & 63, wv = threadIdx.x >> 6;
    if (lane == 0) { r0[wv] = lsum; r1[wv] = sq; }
    __syncthreads();
    if (threadIdx.x == 0) {
        long long S = r0[0] + r0[1] + r0[2] + r0[3];
        long long Q = r1[0] + r1[1] + r1[2] + r1[3];
        float m  = 0.5f  * (float)S / (float)P_TOT;
        float e2 = 0.25f * (float)Q / (float)P_TOT;
        float var = e2 - m * m;
        float a = g[c] * rsqrtf(var + EPSBN);
        A[c]  = 0.5f * a;                                 // y = s*A + B
        Bv[c] = b[c] - m * a;
    }
}

// ==== bn1 + sign + repack: ballot over coalesced short-loads + transpose =====
__global__ __launch_bounds__(256) void bnpack(const short* __restrict__ s,
                                              const float* __restrict__ A,
                                              const float* __restrict__ Bv,
                                              uint64_t* __restrict__ px) {
    __shared__ float sA[256], sB[256];
    sA[threadIdx.x] = A[threadIdx.x];
    sB[threadIdx.x] = Bv[threadIdx.x];
    __syncthreads();
    int wid = blockIdx.x * 4 + (threadIdx.x >> 6);
    int lane = threadIdx.x & 63;
    int wd = wid & 3;
    int g = wid >> 2;
    int n = g / 49, gi = g - n * 49;
    const short* sp = s + ((size_t)n * C + wd * 64) * HW + gi * 64 + lane;
    uint64_t M = 0;
#pragma unroll
    for (int c = 0; c < 64; ++c) {
        float y = (float)sp[(size_t)c * HW] * sA[wd * 64 + c] + sB[wd * 64 + c];
        unsigned long long m = __ballot(y >= 0.0f);
        if (lane == c) M = m;
    }
    M = bt64(M, lane);
    int p = gi * 64 + lane;
    int h = p / WW, w = p - h * WW;
    px[(size_t)wd * NPAD + (size_t)n * PHW + (size_t)(h + 1) * PW + (w + 1)] = M;
}

// ---------------- bn2 + shortcut + hardtanh ----------------------------------
__global__ __launch_bounds__(256) void finalize(const short* __restrict__ s,
                                                const float* __restrict__ x,
                                                const float* __restrict__ A,
                                                const float* __restrict__ Bv,
                                                float* __restrict__ out) {
    int i = blockIdx.x * 256 + threadIdx.x;      // group of 4 elements
    int c = (i / 784) & 255;                     // 784 = 3136/4 groups per plane
    short4 sv = ((const short4*)s)[i];
    float4 xv = ((const float4*)x)[i];
    float a = A[c], bb = Bv[c];
    float4 o;
    o.x = fminf(1.0f, fmaxf(-1.0f, (float)sv.x * a + bb + xv.x));
    o.y = fminf(1.0f, fmaxf(-1.0f, (float)sv.y * a + bb + xv.y));
    o.z = fminf(1.0f, fmaxf(-1.0f, (float)sv.z * a + bb + xv.z));
    o.w = fminf(1.0f, fmaxf(-1.0f, (float)sv.w * a + bb + xv.w));
    ((float4*)out)[i] = o;
}

extern "C" void kernel_launch(void* const* d_in, const int* in_sizes, int n_in,
                              void* d_out, int out_size, void* d_ws, size_t ws_size,
                              hipStream_t stream) {
    const float* x  = (const float*)d_in[0];
    const float* w1 = (const float*)d_in[1];
    const float* g1 = (const float*)d_in[2];
    const float* b1 = (const float*)d_in[3];
    const float* w2 = (const float*)d_in[4];
    const float* g2 = (const float*)d_in[5];
    const float* b2 = (const float*)d_in[6];
    float* out = (float*)d_out;

    // workspace layout (~58.5 MB)
    char* ws = (char*)d_ws;
    uint64_t* pw1 = (uint64_t*)ws;          ws += 4 * 256 * 10 * 8;   // 81,920
    uint64_t* pw2 = (uint64_t*)ws;          ws += 4 * 256 * 10 * 8;
    int* pc1 = (int*)ws;                    ws += 9216 * 4;           // 36,864
    int* pc2 = (int*)ws;                    ws += 9216 * 4;
    unsigned short* K1 = (unsigned short*)ws; ws += 8192;
    unsigned short* K2 = (unsigned short*)ws; ws += 8192;
    float* A1 = (float*)ws;                 ws += 1024;
    float* B1 = (float*)ws;                 ws += 1024;
    float* A2 = (float*)ws;                 ws += 1024;
    float* B2 = (float*)ws;                 ws += 1024;
    uint64_t* px1 = (uint64_t*)ws;          ws += (size_t)4 * NPAD * 8; // 3,444,736
    uint64_t* px2 = (uint64_t*)ws;          ws += (size_t)4 * NPAD * 8;
    short* s16 = (short*)ws;                // 51,380,224

    zero_halo<<<(NPAD + 255) / 256, 256, 0, stream>>>(px1, px2);
    pack_wgt<<<4608, 256, 0, stream>>>(w1, w2, pw1, pw2, pc1, pc2);
    build_K<<<18, 256, 0, stream>>>(pc1, pc2, K1, K2);
    pack_act<<<1568, 256, 0, stream>>>(x, px1);

    bconv<<<dim3(P_TOT / 256, 4), 256, 0, stream>>>(px1, pw1, K1, s16);
    stats<<<C, 256, 0, stream>>>(s16, g1, b1, A1, B1);
    bnpack<<<1568, 256, 0, stream>>>(s16, A1, B1, px2);

    bconv<<<dim3(P_TOT / 256, 4), 256, 0, stream>>>(px2, pw2, K2, s16);
    stats<<<C, 256, 0, stream>>>(s16, g2, b2, A2, B2);

    finalize<<<(P_TOT * C / 4) / 256, 256, 0, stream>>>(s16, x, A2, B2, out);
}

// Round 6
// 539.351 us; speedup vs baseline: 2.1248x; 1.0501x over previous
//
#include <hip/hip_runtime.h>
#include <stdint.h>

// Problem constants (N,C,H,W) = (32,256,56,56), 3x3 conv pad=1 stride=1
#define NB    32
#define C     256
#define HH    56
#define WW    56
#define HW    3136        // 56*56
#define P_TOT 100352      // NB*HW
#define PW    58          // halo-padded width
#define PHW   3364        // 58*58
#define NPAD  107648      // NB*PHW
#define EPSBN 1e-5f

// ---------------- 64-lane u64 shuffle + 64x64 bit-matrix transpose -----------
__device__ __forceinline__ uint64_t shflx64(uint64_t v, int m) {
    int lo = __shfl_xor((int)(uint32_t)v, m, 64);
    int hi = __shfl_xor((int)(uint32_t)(v >> 32), m, 64);
    return ((uint64_t)(uint32_t)hi << 32) | (uint32_t)lo;
}
// Input: lane i holds bits j. Output: lane j holds bits i.
__device__ __forceinline__ uint64_t bt64(uint64_t M, int lane) {
    const uint64_t mk[6] = {0x5555555555555555ULL, 0x3333333333333333ULL,
                            0x0F0F0F0F0F0F0F0FULL, 0x00FF00FF00FF00FFULL,
                            0x0000FFFF0000FFFFULL, 0x00000000FFFFFFFFULL};
#pragma unroll
    for (int k = 0; k < 6; ++k) {
        int s = 1 << k;
        uint64_t mA = mk[k];
        uint64_t v = shflx64(M, s);
        M = (lane & s) ? ((M & ~mA) | ((v & ~mA) >> s))
                       : ((M &  mA) | ((v &  mA) << s));
    }
    return M;
}

// == zero halo cells of both packed-activation buffers + stats accumulators ===
__global__ __launch_bounds__(256) void zero_misc(uint64_t* __restrict__ px1,
                                                 uint64_t* __restrict__ px2,
                                                 int* __restrict__ sS1,
                                                 unsigned long long* __restrict__ sQ1,
                                                 int* __restrict__ sS2,
                                                 unsigned long long* __restrict__ sQ2) {
    int idx = blockIdx.x * 256 + threadIdx.x;
    if (idx < 256) { sS1[idx] = 0; sQ1[idx] = 0; sS2[idx] = 0; sQ2[idx] = 0; }
    if (idx >= NPAD) return;
    int pp = idx % PHW;
    int ph = pp / PW, pw_ = pp - ph * PW;
    if (ph == 0 || ph == PW - 1 || pw_ == 0 || pw_ == PW - 1) {
#pragma unroll
        for (int wd = 0; wd < 4; ++wd) {
            px1[(size_t)wd * NPAD + idx] = 0ull;
            px2[(size_t)wd * NPAD + idx] = 0ull;
        }
    }
}

// ============ pack weights (both sets) via ballot: 1 wave per (set,co,t,wd) ==
// pw layout: [wd][t][co] u64 (coalesced for bconv's per-co load).
__global__ __launch_bounds__(256) void pack_wgt(const float* __restrict__ w1,
                                                const float* __restrict__ w2,
                                                uint64_t* __restrict__ pw1,
                                                uint64_t* __restrict__ pw2,
                                                int* __restrict__ pc1,
                                                int* __restrict__ pc2) {
    int gw = blockIdx.x * 4 + (threadIdx.x >> 6);   // global wave 0..18431
    int lane = threadIdx.x & 63;
    int set = gw / 9216;
    int r = gw - set * 9216;
    int wd = r & 3, q = r >> 2;
    int t = q % 9, co = q / 9;
    const float* w = set ? w2 : w1;
    float v = w[(size_t)co * 2304 + (size_t)(wd * 64 + lane) * 9 + t];
    unsigned long long m = __ballot(v >= 0.0f);
    if (lane == 0) {
        uint64_t* pw = set ? pw2 : pw1;
        int* pc = set ? pc2 : pc1;
        pw[(size_t)(wd * 9 + t) * 256 + co] = m;
        pc[(co * 9 + t) * 4 + wd] = (int)__popcll(m);
    }
}

// ====== border-correction: K[pat][co] = 256*Tvalid + 2*sum_{t inv} popc(w_t) =
__global__ __launch_bounds__(256) void build_K(const int* __restrict__ pc1,
                                               const int* __restrict__ pc2,
                                               unsigned short* __restrict__ K1,
                                               unsigned short* __restrict__ K2) {
    int tid = blockIdx.x * 256 + threadIdx.x;       // 0..4607
    int set = tid / 2304;
    int r = tid - set * 2304;
    int pat = r >> 8, co = r & 255;
    int pv = pat / 3, pq = pat - pv * 3;
    const int* pc = set ? pc2 : pc1;
    int k = 0, corr = 0;
#pragma unroll
    for (int t = 0; t < 9; ++t) {
        int ty = t / 3, tx = t - ty * 3;
        bool inv = (pv == 0 && ty == 0) || (pv == 2 && ty == 2) ||
                   (pq == 0 && tx == 0) || (pq == 2 && tx == 2);
        if (inv) {
            ++k;
            const int* p = pc + (co * 9 + t) * 4;
            corr += p[0] + p[1] + p[2] + p[3];
        }
    }
    unsigned short* K = set ? K2 : K1;
    K[pat * 256 + co] = (unsigned short)(256 * (9 - k) + 2 * corr);
}

// ==== pack activations: ballot over coalesced pixel-loads + bit transpose ====
__global__ __launch_bounds__(256) void pack_act(const float* __restrict__ x,
                                                uint64_t* __restrict__ px) {
    int wid = blockIdx.x * 4 + (threadIdx.x >> 6);  // 0..6271
    int lane = threadIdx.x & 63;
    int wd = wid & 3;
    int g = wid >> 2;                               // 0..1567
    int n = g / 49, gi = g - n * 49;
    const float* xp = x + ((size_t)n * C + wd * 64) * HW + gi * 64 + lane;
    uint64_t M = 0;
#pragma unroll
    for (int c = 0; c < 64; ++c) {
        float v = xp[(size_t)c * HW];
        unsigned long long m = __ballot(v >= 0.0f);
        if (lane == c) M = m;
    }
    M = bt64(M, lane);                              // lane p: bit c = sign
    int p = gi * 64 + lane;
    int h = p / WW, w = p - h * WW;
    px[(size_t)wd * NPAD + (size_t)n * PHW + (size_t)(h + 1) * PW + (w + 1)] = M;
}

// ================= binary conv: thread = co, block = image row ===============
// Weights (36 u64) live in VGPRs; taps are wave-uniform -> scalar loads.
// Output channel-last s16[p][co]; BN stats fused via integer atomics.
__global__ __launch_bounds__(256, 4) void bconv(const uint64_t* __restrict__ px,
                                                const uint64_t* __restrict__ pw,
                                                const unsigned short* __restrict__ Kt,
                                                short* __restrict__ sout,
                                                int* __restrict__ sS,
                                                unsigned long long* __restrict__ sQ) {
    __shared__ unsigned short Kl[2304];
    int co = threadIdx.x;
#pragma unroll 1
    for (int i = threadIdx.x; i < 2304; i += 256) Kl[i] = Kt[i];

    uint64_t wv[4][9];
#pragma unroll
    for (int wd = 0; wd < 4; ++wd)
#pragma unroll
        for (int t = 0; t < 9; ++t)
            wv[wd][t] = pw[(size_t)(wd * 9 + t) * 256 + co];
    __syncthreads();

    int row = blockIdx.x;                           // 0..1791
    int n = row / HH, h = row - n * HH;
    size_t base = (size_t)n * PHW + (size_t)(h + 1) * PW + 1;
    short* orow = sout + (size_t)(n * HW + h * WW) * C + co;
    const bool irow = (h > 0) && (h < HH - 1);
    int pv = (h == 0) ? 0 : ((h == HH - 1) ? 2 : 1);

    int ssum = 0, ssq = 0;
#pragma unroll 2
    for (int w = 0; w < WW; ++w) {
        int acc = 0;
#pragma unroll
        for (int wd = 0; wd < 4; ++wd) {
            const uint64_t* xb = px + (size_t)wd * NPAD + base + w;
            uint64_t t0 = xb[-PW - 1], t1 = xb[-PW], t2 = xb[-PW + 1];
            uint64_t t3 = xb[-1],      t4 = xb[0],   t5 = xb[1];
            uint64_t t6 = xb[PW - 1],  t7 = xb[PW],  t8 = xb[PW + 1];
            int r = 0;
            r += __popcll(t0 ^ wv[wd][0]);
            r += __popcll(t1 ^ wv[wd][1]);
            r += __popcll(t2 ^ wv[wd][2]);
            r += __popcll(t3 ^ wv[wd][3]);
            r += __popcll(t4 ^ wv[wd][4]);
            r += __popcll(t5 ^ wv[wd][5]);
            r += __popcll(t6 ^ wv[wd][6]);
            r += __popcll(t7 ^ wv[wd][7]);
            r += __popcll(t8 ^ wv[wd][8]);
            acc += r;
        }
        int dot;
        if (irow && w > 0 && w < WW - 1) {          // wave-uniform branch
            dot = 2304 - 2 * acc;
        } else {
            int pq = (w == 0) ? 0 : ((w == WW - 1) ? 2 : 1);
            dot = (int)Kl[(pv * 3 + pq) * 256 + co] - 2 * acc;
        }
        orow[(size_t)w * C] = (short)dot;
        ssum += dot;
        ssq += dot * dot;                           // <= 3.0e8, fits i32
    }
    atomicAdd(sS + co, ssum);
    atomicAdd(sQ + co, (unsigned long long)(unsigned int)ssq);
}

// ===== finalize BN coefficients from fused integer sums ======================
// y = dot*A[c] + B[c]  with  A = 0.5*g*rsqrt(var+eps), B = b - m*(2A)
__global__ __launch_bounds__(256) void bnAB(const int* __restrict__ sS,
                                            const unsigned long long* __restrict__ sQ,
                                            const float* __restrict__ g,
                                            const float* __restrict__ b,
                                            float* __restrict__ A,
                                            float* __restrict__ Bv) {
    int c = threadIdx.x;
    float S = (float)sS[c];
    float Q = (float)sQ[c];
    float m  = 0.5f  * S / (float)P_TOT;
    float e2 = 0.25f * Q / (float)P_TOT;
    float var = e2 - m * m;
    float a = g[c] * rsqrtf(var + EPSBN);
    A[c]  = 0.5f * a;
    Bv[c] = b[c] - m * a;
}

// ==== bn1 + sign + repack: channel-last rows, direct in-thread bit build =====
__global__ __launch_bounds__(256) void bnpack(const short* __restrict__ s,
                                              const float* __restrict__ A,
                                              const float* __restrict__ Bv,
                                              uint64_t* __restrict__ px) {
    int p = blockIdx.x * 256 + threadIdx.x;         // 0..P_TOT-1
    const int4* sp = (const int4*)(s + (size_t)p * C);
    uint32_t bits[8];
#pragma unroll
    for (int wd = 0; wd < 8; ++wd) bits[wd] = 0u;
#pragma unroll 4
    for (int j = 0; j < 32; ++j) {
        int4 v = sp[j];
#pragma unroll
        for (int k = 0; k < 4; ++k) {
            int u = (&v.x)[k];
            int c = j * 8 + k * 2;
            float y0 = (float)(short)(u & 0xFFFF) * A[c] + Bv[c];
            float y1 = (float)(u >> 16) * A[c + 1] + Bv[c + 1];
            if (y0 >= 0.0f) bits[c >> 5] |= (1u << (c & 31));
            if (y1 >= 0.0f) bits[(c + 1) >> 5] |= (1u << ((c + 1) & 31));
        }
    }
    int n = p / HW, rem = p - n * HW;
    int h = rem / WW, w = rem - h * WW;
    size_t pidx = (size_t)n * PHW + (size_t)(h + 1) * PW + (w + 1);
#pragma unroll
    for (int wd = 0; wd < 4; ++wd)
        px[(size_t)wd * NPAD + pidx] =
            ((uint64_t)bits[2 * wd + 1] << 32) | bits[2 * wd];
}

// ==== bn2 + shortcut + hardtanh: LDS-transposed tile, all streams coalesced ==
__global__ __launch_bounds__(256) void finalize(const short* __restrict__ s,
                                                const float* __restrict__ x,
                                                const float* __restrict__ A,
                                                const float* __restrict__ Bv,
                                                float* __restrict__ out) {
    __shared__ int4 lds4[2048];                     // 64 pixels x 512B, slot-swizzled
    int tid = threadIdx.x;
    int p0 = blockIdx.x * 64;
    int n = p0 / HW, rem0 = p0 - n * HW;
    const int4* s4 = (const int4*)(s + (size_t)p0 * C);
#pragma unroll
    for (int it = 0; it < 8; ++it) {
        int u = tid + it * 256;
        int r = u >> 5, j = u & 31;
        int4 v = s4[r * 32 + j];
        lds4[r * 32 + ((j + r) & 31)] = v;          // swizzle: conflict-light reads
    }
    __syncthreads();
    int lane = tid & 63;
    int wvn = tid >> 6;
#pragma unroll 4
    for (int it = 0; it < 64; ++it) {
        int c = it * 4 + wvn;
        int slot = ((c >> 3) + lane) & 31;
        short sv = ((const short*)lds4)[lane * 256 + slot * 8 + (c & 7)];
        size_t gi = ((size_t)n * C + c) * HW + rem0 + lane;
        float y = (float)sv * A[c] + Bv[c] + x[gi];
        out[gi] = fminf(1.0f, fmaxf(-1.0f, y));
    }
}

extern "C" void kernel_launch(void* const* d_in, const int* in_sizes, int n_in,
                              void* d_out, int out_size, void* d_ws, size_t ws_size,
                              hipStream_t stream) {
    const float* x  = (const float*)d_in[0];
    const float* w1 = (const float*)d_in[1];
    const float* g1 = (const float*)d_in[2];
    const float* b1 = (const float*)d_in[3];
    const float* w2 = (const float*)d_in[4];
    const float* g2 = (const float*)d_in[5];
    const float* b2 = (const float*)d_in[6];
    float* out = (float*)d_out;

    // workspace layout (~58.5 MB)
    char* ws = (char*)d_ws;
    uint64_t* pw1 = (uint64_t*)ws;            ws += 4 * 9 * 256 * 8;      // 73,728
    uint64_t* pw2 = (uint64_t*)ws;            ws += 4 * 9 * 256 * 8;
    int* pc1 = (int*)ws;                      ws += 9216 * 4;             // 36,864
    int* pc2 = (int*)ws;                      ws += 9216 * 4;
    unsigned short* K1 = (unsigned short*)ws; ws += 8192;
    unsigned short* K2 = (unsigned short*)ws; ws += 8192;
    float* A1 = (float*)ws;                   ws += 1024;
    float* B1 = (float*)ws;                   ws += 1024;
    float* A2 = (float*)ws;                   ws += 1024;
    float* B2 = (float*)ws;                   ws += 1024;
    int* sS1 = (int*)ws;                      ws += 1024;
    int* sS2 = (int*)ws;                      ws += 1024;
    unsigned long long* sQ1 = (unsigned long long*)ws; ws += 2048;
    unsigned long long* sQ2 = (unsigned long long*)ws; ws += 2048;
    uint64_t* px1 = (uint64_t*)ws;            ws += (size_t)4 * NPAD * 8; // 3,444,736
    uint64_t* px2 = (uint64_t*)ws;            ws += (size_t)4 * NPAD * 8;
    short* s16 = (short*)ws;                  // 51,380,224 (channel-last [p][co])

    zero_misc<<<(NPAD + 255) / 256, 256, 0, stream>>>(px1, px2, sS1, sQ1, sS2, sQ2);
    pack_wgt<<<4608, 256, 0, stream>>>(w1, w2, pw1, pw2, pc1, pc2);
    build_K<<<18, 256, 0, stream>>>(pc1, pc2, K1, K2);
    pack_act<<<1568, 256, 0, stream>>>(x, px1);

    bconv<<<NB * HH, 256, 0, stream>>>(px1, pw1, K1, s16, sS1, sQ1);
    bnAB<<<1, 256, 0, stream>>>(sS1, sQ1, g1, b1, A1, B1);
    bnpack<<<P_TOT / 256, 256, 0, stream>>>(s16, A1, B1, px2);

    bconv<<<NB * HH, 256, 0, stream>>>(px2, pw2, K2, s16, sS2, sQ2);
    bnAB<<<1, 256, 0, stream>>>(sS2, sQ2, g2, b2, A2, B2);

    finalize<<<P_TOT / 64, 256, 0, stream>>>(s16, x, A2, B2, out);
}